// Round 11
// baseline (84.663 us; speedup 1.0000x reference)
//
#include <hip/hip_runtime.h>

#define D_FEAT 32
#define RSH 8              // 256 nodes per range
#define RS_NODES 256
#define LOCAL_SHIFT 24     // pack: src | (dst&255)<<24  (needs N <= 2^24)
#define SRC_MASK 0x00FFFFFFu
#define NR_PAD 512         // scan width / max ranges (N <= 131072)
#define BF_CHUNK 3328      // edges staged per binfuse block
#define GATHER_BLOCKS 2048 // persistent gather grid

// round-to-nearest-even bf16 pack of two floats
__device__ __forceinline__ unsigned bfpack(float lo, float hi) {
    unsigned ul = __float_as_uint(lo), uh = __float_as_uint(hi);
    ul = (ul + 0x7FFFu + ((ul >> 16) & 1u)) >> 16;
    uh = (uh + 0x7FFFu + ((uh >> 16) & 1u)) >> 16;
    return ul | (uh << 16);
}

__device__ __forceinline__ void bfadd(float4& a, uint2 w) {
    a.x += __uint_as_float(w.x << 16);
    a.y += __uint_as_float(w.x & 0xFFFF0000u);
    a.z += __uint_as_float(w.y << 16);
    a.w += __uint_as_float(w.y & 0xFFFF0000u);
}

// Fused single-pass binning: stage chunk in LDS, histogram by range, reserve per-range
// space with ONE global atomic per (block,range), place via LDS cursors into
// capacity-padded per-range segments binned[r*CAP ...]. Replaces binA+scanA+scanR+binB.
__global__ void binfuse_kernel(const int* __restrict__ src, const int* __restrict__ dst,
                               unsigned* __restrict__ cnt,     // [NR], pre-zeroed
                               unsigned* __restrict__ binned,  // [NR*CAP]
                               int E, int NR, int CAP) {
    __shared__ unsigned sedge[BF_CHUNK];
    __shared__ unsigned short skey[BF_CHUNK];
    __shared__ unsigned hist[NR_PAD];
    __shared__ unsigned base_l[NR_PAD];
    int lo = blockIdx.x * BF_CHUNK;
    int n = min(BF_CHUNK, E - lo);
    if (n <= 0) return;
    for (int i = threadIdx.x; i < NR; i += blockDim.x) hist[i] = 0u;
    __syncthreads();
    for (int i = threadIdx.x; i < n; i += blockDim.x) {
        int s = src[lo + i];
        int d = dst[lo + i];
        sedge[i] = (unsigned)s | ((unsigned)(d & (RS_NODES - 1)) << LOCAL_SHIFT);
        unsigned r = (unsigned)d >> RSH;
        skey[i] = (unsigned short)r;
        atomicAdd(&hist[r], 1u);
    }
    __syncthreads();
    // reserve
    for (int r = threadIdx.x; r < NR; r += blockDim.x) {
        unsigned c = hist[r];
        base_l[r] = c ? atomicAdd(&cnt[r], c) : 0u;
    }
    __syncthreads();
    for (int i = threadIdx.x; i < NR; i += blockDim.x) hist[i] = 0u;
    __syncthreads();
    // place
    for (int i = threadIdx.x; i < n; i += blockDim.x) {
        unsigned r = skey[i];
        unsigned off = base_l[r] + atomicAdd(&hist[r], 1u);
        if (off < (unsigned)CAP)  // safety clamp (never triggers with 1.5x+ padding)
            binned[(size_t)r * CAP + off] = sedge[i];
    }
}

// Build per-node CSR within each 256-node range: dense-offset scan over cnt[],
// count -> 256-wide block scan -> place into DENSE csr, emit ni[n]={densestart,inv},
// and convert rows to pre-scaled bf16 wf[n] = bf16(inv[n]*feat[n]).
__global__ void build_kernel(const unsigned* __restrict__ binned, const unsigned* __restrict__ cnt,
                             const float* __restrict__ feat, unsigned* __restrict__ wf,
                             unsigned* __restrict__ csr, uint2* __restrict__ ni,
                             int N, int E, int NR, int CAP) {
    __shared__ unsigned sc[2][NR_PAD];
    __shared__ unsigned deg_l[RS_NODES];
    __shared__ unsigned cur_l[RS_NODES];
    __shared__ float sinv[RS_NODES];
    __shared__ unsigned wtot[4];
    int r = blockIdx.x;
    int tid = threadIdx.x;  // 256
    // inclusive scan of cnt over NR_PAD slots (512), 2 slots/thread
    sc[0][tid]       = (tid < NR)       ? min(cnt[tid], (unsigned)CAP)       : 0u;
    sc[0][tid + 256] = (tid + 256 < NR) ? min(cnt[tid + 256], (unsigned)CAP) : 0u;
    int pin = 0;
    for (int off = 1; off < NR_PAD; off <<= 1) {
        __syncthreads();
        int po = pin ^ 1;
        #pragma unroll
        for (int k = 0; k < 2; k++) {
            int idx = tid + k * 256;
            unsigned x = sc[pin][idx];
            if (idx >= off) x += sc[pin][idx - off];
            sc[po][idx] = x;
        }
        pin ^= 1;
    }
    __syncthreads();
    unsigned dense0 = (r == 0) ? 0u : sc[pin][r - 1];  // exclusive dense start of range r
    unsigned cntr = min(cnt[r], (unsigned)CAP);
    size_t seg = (size_t)r * CAP;
    deg_l[tid] = 0u;
    __syncthreads();
    for (unsigned e = tid; e < cntr; e += RS_NODES)
        atomicAdd(&deg_l[binned[seg + e] >> LOCAL_SHIFT], 1u);
    __syncthreads();
    unsigned d = deg_l[tid];
    int lane = tid & 63, w = tid >> 6;
    unsigned incl = d;
    #pragma unroll
    for (int off = 1; off < 64; off <<= 1) {
        unsigned t = __shfl_up(incl, off, 64);
        if (lane >= off) incl += t;
    }
    if (lane == 63) wtot[w] = incl;
    __syncthreads();
    unsigned woff = 0;
    #pragma unroll
    for (int i = 0; i < 4; i++) if (i < w) woff += wtot[i];
    unsigned base = dense0 + woff + incl - d;   // dense exclusive position for node tid
    cur_l[tid] = base;
    float ivv = rsqrtf(1.0f + (float)d);
    sinv[tid] = ivv;
    int node = r * RS_NODES + tid;
    if (node < N) ni[node] = make_uint2(base, __float_as_uint(ivv));
    if (r == 0 && tid == 0) ni[N] = make_uint2((unsigned)E, 0u);
    __syncthreads();
    for (unsigned e = tid; e < cntr; e += RS_NODES) {
        unsigned p = binned[seg + e];
        unsigned pos = atomicAdd(&cur_l[p >> LOCAL_SHIFT], 1u);
        csr[pos] = p & SRC_MASK;
    }
    // wf conversion: 256 nodes x 4 quads (each quad = 8 dims -> one uint4)
    for (int i = tid; i < RS_NODES * 4; i += RS_NODES) {
        int nl = i >> 2, q = i & 3;
        int nn = r * RS_NODES + nl;
        if (nn < N) {
            float iw = sinv[nl];
            const float4* fp = (const float4*)(feat + (size_t)nn * D_FEAT + q * 8);
            float4 a = fp[0], b = fp[1];
            uint4 o;
            o.x = bfpack(iw * a.x, iw * a.y);
            o.y = bfpack(iw * a.z, iw * a.w);
            o.z = bfpack(iw * b.x, iw * b.y);
            o.w = bfpack(iw * b.z, iw * b.w);
            ((uint4*)wf)[(size_t)nn * 4 + q] = o;
        }
    }
}

// PERSISTENT gather (unchanged from round 10): straight-line predicated 16-slot body,
// self-loop from wf, nodeinfo uint2 carried across the node loop.
__global__ void gather_kernel(const unsigned* __restrict__ wf, const unsigned* __restrict__ csr,
                              const uint2* __restrict__ ni, float* __restrict__ out,
                              int N, int per) {
    int w = blockIdx.x * (blockDim.x >> 6) + (threadIdx.x >> 6);
    int lane = threadIdx.x & 63;
    int g = lane >> 3;
    int q = lane & 7;
    int n0 = w * per;
    int n1 = min(N, n0 + per);
    if (n0 >= n1) return;
    uint2 cur = ni[n0];
    for (int node = n0; node < n1; ++node) {
        uint2 nxt = ni[node + 1];
        unsigned start = cur.x, end = nxt.x;
        float iv = __uint_as_float(cur.y);
        float4 acc = make_float4(0.f, 0.f, 0.f, 0.f);
        uint2 ws = *(const uint2*)(wf + (size_t)node * 16 + q * 2);
        if (g == 0) bfadd(acc, ws);
        unsigned k0 = start + g, k1 = start + 8 + g;
        unsigned j0 = (k0 < end) ? csr[k0] : (unsigned)node;
        unsigned j1 = (k1 < end) ? csr[k1] : (unsigned)node;
        uint2 w0 = *(const uint2*)(wf + (size_t)j0 * 16 + q * 2);
        uint2 w1 = *(const uint2*)(wf + (size_t)j1 * 16 + q * 2);
        if (k0 < end) bfadd(acc, w0);
        if (k1 < end) bfadd(acc, w1);
        unsigned k = start + 16 + g;
        if (k < end) {
            for (; k + 8 < end; k += 16) {
                unsigned ja = csr[k], jb = csr[k + 8];
                uint2 wa = *(const uint2*)(wf + (size_t)ja * 16 + q * 2);
                uint2 wb = *(const uint2*)(wf + (size_t)jb * 16 + q * 2);
                bfadd(acc, wa);
                bfadd(acc, wb);
            }
            if (k < end) {
                unsigned jc = csr[k];
                uint2 wc = *(const uint2*)(wf + (size_t)jc * 16 + q * 2);
                bfadd(acc, wc);
            }
        }
        #pragma unroll
        for (int off = 8; off < 64; off <<= 1) {
            acc.x += __shfl_xor(acc.x, off);
            acc.y += __shfl_xor(acc.y, off);
            acc.z += __shfl_xor(acc.z, off);
            acc.w += __shfl_xor(acc.w, off);
        }
        if (g == 0) {
            float4 rv;
            rv.x = iv * acc.x; rv.y = iv * acc.y; rv.z = iv * acc.z; rv.w = iv * acc.w;
            *(float4*)(out + (size_t)node * D_FEAT + q * 4) = rv;
        }
        cur = nxt;
    }
}

// ---------- fallback (atomic scatter) if workspace too small ----------

__global__ void fb_deg_kernel(const int* __restrict__ dst, float* __restrict__ deg, int E) {
    int i = blockIdx.x * blockDim.x + threadIdx.x;
    int stride = gridDim.x * blockDim.x;
    for (; i < E; i += stride) atomicAdd(&deg[dst[i]], 1.0f);
}
__global__ void fb_inv_kernel(const float* __restrict__ deg, float* __restrict__ inv, int N) {
    int i = blockIdx.x * blockDim.x + threadIdx.x;
    if (i < N) inv[i] = rsqrtf(1.0f + deg[i]);
}
__global__ void fb_scatter_kernel(const float* __restrict__ feat, const int* __restrict__ src,
                                  const int* __restrict__ dst, const float* __restrict__ inv,
                                  float* __restrict__ out, int E) {
    long long tid = (long long)blockIdx.x * blockDim.x + threadIdx.x;
    int e = (int)(tid >> 5);
    int d = (int)(tid & 31);
    if (e >= E) return;
    int s = src[e];
    int t = dst[e];
    atomicAdd(&out[t * D_FEAT + d], inv[s] * feat[s * D_FEAT + d]);
}
__global__ void fb_finalize_kernel(const float* __restrict__ feat, const float* __restrict__ inv,
                                   float* __restrict__ out, int ND) {
    int tid = blockIdx.x * blockDim.x + threadIdx.x;
    if (tid >= ND) return;
    float iv = inv[tid >> 5];
    out[tid] = iv * (out[tid] + iv * feat[tid]);
}

extern "C" void kernel_launch(void* const* d_in, const int* in_sizes, int n_in,
                              void* d_out, int out_size, void* d_ws, size_t ws_size,
                              hipStream_t stream) {
    const float* feat = (const float*)d_in[0];
    const int* esrc = (const int*)d_in[1];
    const int* edst = (const int*)d_in[2];
    float* out = (float*)d_out;

    const int N = in_sizes[0] / D_FEAT;
    const int E = in_sizes[1];
    const int ND = N * D_FEAT;
    const int NR = (N + RS_NODES - 1) >> RSH;

    // capacity-padded per-range segments: mean*1.5 + 256, rounded to 64
    int CAP = (E + NR - 1) / NR;
    CAP = CAP + CAP / 2 + 256;
    CAP = (CAP + 63) & ~63;

    // layout (words): cnt[NR] | binned[NR*CAP] | csr[E] | wf[16N] (16B-align) | ni[2(N+1)] (8B-align)
    size_t binned_off = NR;
    size_t csr_off = binned_off + (size_t)NR * CAP;
    size_t wf_off = (csr_off + (size_t)E + 3) & ~(size_t)3;
    size_t ni_off = (wf_off + 16 * (size_t)N + 1) & ~(size_t)1;
    size_t need = (ni_off + 2 * ((size_t)N + 1)) * 4;

    if (ws_size >= need && NR <= NR_PAD && N <= (1 << LOCAL_SHIFT)) {
        unsigned* ws_u   = (unsigned*)d_ws;
        unsigned* cnt    = ws_u;
        unsigned* binned = ws_u + binned_off;
        unsigned* csr    = ws_u + csr_off;
        unsigned* wf     = ws_u + wf_off;
        uint2*    ni     = (uint2*)(ws_u + ni_off);

        hipMemsetAsync(cnt, 0, (size_t)NR * sizeof(unsigned), stream);
        {
            int grid = (E + BF_CHUNK - 1) / BF_CHUNK;
            binfuse_kernel<<<grid, 256, 0, stream>>>(esrc, edst, cnt, binned, E, NR, CAP);
        }
        build_kernel<<<NR, RS_NODES, 0, stream>>>(binned, cnt, feat, wf, csr, ni, N, E, NR, CAP);
        {
            int total_waves = GATHER_BLOCKS * 4;
            int per = (N + total_waves - 1) / total_waves;
            gather_kernel<<<GATHER_BLOCKS, 256, 0, stream>>>(wf, csr, ni, out, N, per);
        }
    } else {
        float* deg = (float*)d_ws;
        float* inv = deg + N;
        hipMemsetAsync(deg, 0, (size_t)N * sizeof(float), stream);
        hipMemsetAsync(out, 0, (size_t)ND * sizeof(float), stream);
        {
            int grid = (E + 255) / 256; if (grid > 2048) grid = 2048;
            fb_deg_kernel<<<grid, 256, 0, stream>>>(edst, deg, E);
        }
        fb_inv_kernel<<<(N + 255) / 256, 256, 0, stream>>>(deg, inv, N);
        {
            long long total = (long long)E * D_FEAT;
            fb_scatter_kernel<<<(int)((total + 255) / 256), 256, 0, stream>>>(feat, esrc, edst, inv, out, E);
        }
        fb_finalize_kernel<<<(ND + 255) / 256, 256, 0, stream>>>(feat, inv, out, ND);
    }
}